// Round 1
// baseline (2810.117 us; speedup 1.0000x reference)
//
#include <hip/hip_runtime.h>
#include <stdint.h>

// Problem constants
#define BB     64
#define NPTS   1024
#define DIM    256
#define BOOKN  2048
#define NC     16
#define NROWS  (BB*NPTS)           // 65536
#define HALF_N 67108864u           // NROWS*BOOKN/2
#define HALF_ROWS 32768            // NROWS/2

// d_out layout (floats): [zq | precision_q | logits | mu_mix]
#define OFF_PQ ((size_t)NROWS*DIM)            // 16777216
#define OFF_LG (OFF_PQ + 1)                   // 16777217
#define OFF_MM (OFF_LG + (size_t)NROWS*BOOKN) // 150994945

// ws layout (floats): bn[2048], rn[65536], pq[1]  => ~270 KB needed
#define WS_RN 2048
#define WS_PQ (2048 + NROWS)

// ---------------- threefry2x32-20, JAX semantics, key = (0, 42) -------------
__device__ __forceinline__ uint32_t rotl32(uint32_t x, int r){
  return (x << r) | (x >> (32 - r));
}

__device__ __forceinline__ void threefry_0_42(uint32_t x0, uint32_t x1,
                                              uint32_t& o0, uint32_t& o1){
  const uint32_t ks0 = 0u;
  const uint32_t ks1 = 42u;
  const uint32_t ks2 = 0u ^ 42u ^ 0x1BD11BDAu;
  x0 += ks0; x1 += ks1;
#define TF_R(r) { x0 += x1; x1 = rotl32(x1, r); x1 ^= x0; }
  TF_R(13) TF_R(15) TF_R(26) TF_R(6)
  x0 += ks1; x1 += ks2 + 1u;
  TF_R(17) TF_R(29) TF_R(16) TF_R(24)
  x0 += ks2; x1 += ks0 + 2u;
  TF_R(13) TF_R(15) TF_R(26) TF_R(6)
  x0 += ks0; x1 += ks1 + 3u;
  TF_R(17) TF_R(29) TF_R(16) TF_R(24)
  x0 += ks1; x1 += ks2 + 4u;
  TF_R(13) TF_R(15) TF_R(26) TF_R(6)
  x0 += ks2; x1 += ks0 + 5u;
#undef TF_R
  o0 = x0; o1 = x1;
}

__device__ __forceinline__ float gumbel_from_bits(uint32_t bits){
  // jax uniform: bitcast((bits>>9)|0x3f800000) - 1.0  in [0,1)
  float u = __uint_as_float((bits >> 9) | 0x3f800000u) - 1.0f;
  return -logf(-logf(u + 1e-10f) + 1e-10f);
}

// ---------------- K0: book norms + precision_q ------------------------------
__global__ __launch_bounds__(256) void k_prep(const float* __restrict__ book,
    const float* __restrict__ lpq, float* __restrict__ bn,
    float* __restrict__ ws_pq, float* __restrict__ pq_out)
{
  __shared__ float red[4];
  const int j = blockIdx.x, t = threadIdx.x;
  float v = book[(size_t)j*DIM + t];
  float s = v*v;
  #pragma unroll
  for (int o = 32; o; o >>= 1) s += __shfl_down(s, o, 64);
  const int wv = t >> 6, ln = t & 63;
  if (ln == 0) red[wv] = s;
  __syncthreads();
  if (t == 0){
    bn[j] = red[0] + red[1] + red[2] + red[3];
    if (j == 0){
      float pq = fmaxf(expf(lpq[0]), 1e-10f);
      float prec = 0.5f / pq;
      ws_pq[0] = prec;
      pq_out[0] = prec;
    }
  }
}

// ---------------- K1: mu_mix, zp (into zq slot), row norms ------------------
__global__ __launch_bounds__(256) void k_mix(const float* __restrict__ z,
    const float* __restrict__ cp, const float* __restrict__ mu,
    float* __restrict__ zp, float* __restrict__ mm, float* __restrict__ rn)
{
  __shared__ float s_cp[BB*NC];   // 1024
  __shared__ float s_red[4];
  const int n = blockIdx.x;
  const int t = threadIdx.x;      // = d
  for (int e = t; e < BB*NC; e += 256) s_cp[e] = cp[e];
  float muv[NC];
  #pragma unroll
  for (int c = 0; c < NC; ++c) muv[c] = mu[(size_t)(c*NPTS + n)*DIM + t];
  __syncthreads();
  const int wv = t >> 6, ln = t & 63;
  for (int b = 0; b < BB; ++b){
    float m = 0.f;
    #pragma unroll
    for (int c = 0; c < NC; ++c) m = fmaf(s_cp[b*NC + c], muv[c], m);
    const size_t idx = ((size_t)(b*NPTS + n))*DIM + t;
    const float zpv = z[idx] + m;
    mm[idx] = m;
    zp[idx] = zpv;
    float s = zpv*zpv;
    #pragma unroll
    for (int o = 32; o; o >>= 1) s += __shfl_down(s, o, 64);
    if (ln == 0) s_red[wv] = s;
    __syncthreads();
    if (t == 0) rn[b*NPTS + n] = s_red[0] + s_red[1] + s_red[2] + s_red[3];
    __syncthreads();
  }
}

// ---------------- K2: logits GEMM (f32, 64x128 tile, KC=32) -----------------
#define IT 64
#define JT 128
#define KC 32
__global__ __launch_bounds__(256) void k_logits(const float* __restrict__ zp,
    const float* __restrict__ book, const float* __restrict__ rn,
    const float* __restrict__ bn, const float* __restrict__ ws_pq,
    float* __restrict__ logits)
{
  __shared__ float sA[KC][IT+4];   // zp^T  [k][i], 16B-aligned rows
  __shared__ float sB[KC][JT+4];   // book^T [k][j]
  const int t  = threadIdx.x;
  const int i0 = blockIdx.y * IT;
  const int j0 = blockIdx.x * JT;
  const int tx = t & 15;   // col group (8 cols)
  const int ty = t >> 4;   // row group (4 rows)
  float acc[4][8];
  #pragma unroll
  for (int r = 0; r < 4; ++r)
    #pragma unroll
    for (int c = 0; c < 8; ++c) acc[r][c] = 0.f;

  for (int k0 = 0; k0 < DIM; k0 += KC){
    #pragma unroll
    for (int e = 0; e < 8; ++e){
      int idx = e*256 + t;
      int kk = idx & (KC-1), ii = idx >> 5;
      sA[kk][ii] = zp[(size_t)(i0+ii)*DIM + k0 + kk];
    }
    #pragma unroll
    for (int e = 0; e < 16; ++e){
      int idx = e*256 + t;
      int kk = idx & (KC-1), jj = idx >> 5;
      sB[kk][jj] = book[(size_t)(j0+jj)*DIM + k0 + kk];
    }
    __syncthreads();
    #pragma unroll
    for (int kk = 0; kk < KC; ++kk){
      const float4 av  = *(const float4*)&sA[kk][ty*4];
      const float4 bv0 = *(const float4*)&sB[kk][tx*8];
      const float4 bv1 = *(const float4*)&sB[kk][tx*8+4];
      const float a[4] = {av.x, av.y, av.z, av.w};
      const float b[8] = {bv0.x,bv0.y,bv0.z,bv0.w,bv1.x,bv1.y,bv1.z,bv1.w};
      #pragma unroll
      for (int r = 0; r < 4; ++r)
        #pragma unroll
        for (int c = 0; c < 8; ++c) acc[r][c] = fmaf(a[r], b[c], acc[r][c]);
    }
    __syncthreads();
  }
  const float pq = ws_pq[0];
  #pragma unroll
  for (int r = 0; r < 4; ++r){
    const int i = i0 + ty*4 + r;
    const float rni = rn[i];
    const size_t base = (size_t)i*BOOKN + j0 + tx*8;
    #pragma unroll
    for (int c = 0; c < 8; ++c){
      const int j = j0 + tx*8 + c;
      logits[base + c] = -pq * (rni + bn[j] - 2.0f*acc[r][c]);
    }
  }
}

// ---------------- K3: fused gumbel-softmax + zq GEMM ------------------------
// Block: 32 first-half rows (i0..i0+31) paired with rows +32768 (threefry
// pairing), all 2048 book cols, all 256 dims. Deferred 1/S normalization.
#define KC3 32
__global__ __launch_bounds__(256) void k_zq(const float* __restrict__ logits,
    const float* __restrict__ book, const int* __restrict__ temp,
    float* __restrict__ zq)
{
  __shared__ float sBk[KC3][DIM+4];   // book chunk [j][d]
  __shared__ float sP[64][KC3+1];     // p~ tile (64 rows)
  __shared__ float sM[64];
  __shared__ float sS[64][8];
  __shared__ float sInv[64];
  const int t  = threadIdx.x;
  const int i0 = blockIdx.x * 32;     // first-half base row
  const float tinv = 1.0f / (float)temp[0];

  // Pass 1: per-row max of logits (shift bound; +17 covers max gumbel ~16.64)
  {
    const int wv = t >> 6, ln = t & 63;
    for (int rr = 0; rr < 16; ++rr){
      const int r = wv*16 + rr;
      const int gi = (r < 32) ? (i0 + r) : (i0 + r - 32 + HALF_ROWS);
      const float* row = logits + (size_t)gi*BOOKN;
      float mx = -3.4e38f;
      #pragma unroll 4
      for (int e = 0; e < 32; ++e) mx = fmaxf(mx, row[e*64 + ln]);
      #pragma unroll
      for (int o = 32; o; o >>= 1) mx = fmaxf(mx, __shfl_down(mx, o, 64));
      if (ln == 0) sM[r] = mx + 17.0f;
    }
  }
  __syncthreads();

  const int td  = t & 31;        // d group: d = td*8 .. +7
  const int tg  = t >> 5;        // row group: rows tg*8 .. +7
  const int srA = t >> 3;        // staging row (0..31)
  const int sj0 = (t & 7) * 4;   // staging col start
  const int giA = i0 + srA;
  const float mA = sM[srA];
  const float mB = sM[srA + 32];
  float acc[8][8];
  #pragma unroll
  for (int r = 0; r < 8; ++r)
    #pragma unroll
    for (int c = 0; c < 8; ++c) acc[r][c] = 0.f;
  float sumA = 0.f, sumB = 0.f;

  for (int j0 = 0; j0 < BOOKN; j0 += KC3){
    // stage book chunk
    #pragma unroll
    for (int e = 0; e < 32; ++e){
      int idx = e*256 + t;
      int d = idx & 255, jj = idx >> 8;
      sBk[jj][d] = book[(size_t)(j0+jj)*DIM + d];
    }
    // stage p~ for paired rows (one threefry call -> two rows)
    #pragma unroll
    for (int e = 0; e < 4; ++e){
      const int jc = sj0 + e;
      const int j  = j0 + jc;
      const uint32_t p = (uint32_t)(giA*BOOKN + j);   // < HALF_N
      uint32_t o0, o1;
      threefry_0_42(p, p + HALF_N, o0, o1);
      const float gA = gumbel_from_bits(o0);
      const float gB = gumbel_from_bits(o1);
      const float lA = logits[(size_t)giA*BOOKN + j];
      const float lB = logits[(size_t)(giA+HALF_ROWS)*BOOKN + j];
      const float pA = expf((lA + gA - mA)*tinv);
      const float pB = expf((lB + gB - mB)*tinv);
      sP[srA][jc]      = pA;
      sP[srA + 32][jc] = pB;
      sumA += pA;
      sumB += pB;
    }
    __syncthreads();
    // GEMM chunk
    for (int jc = 0; jc < KC3; ++jc){
      float pv[8];
      #pragma unroll
      for (int r = 0; r < 8; ++r) pv[r] = sP[tg*8 + r][jc];
      const float4 b0 = *(const float4*)&sBk[jc][td*8];
      const float4 b1 = *(const float4*)&sBk[jc][td*8+4];
      const float bb[8] = {b0.x,b0.y,b0.z,b0.w,b1.x,b1.y,b1.z,b1.w};
      #pragma unroll
      for (int r = 0; r < 8; ++r)
        #pragma unroll
        for (int c = 0; c < 8; ++c) acc[r][c] = fmaf(pv[r], bb[c], acc[r][c]);
    }
    __syncthreads();
  }

  // S reduction (8 partials per row)
  sS[srA][t & 7]      = sumA;
  sS[srA + 32][t & 7] = sumB;
  __syncthreads();
  if (t < 64){
    float s = 0.f;
    #pragma unroll
    for (int e = 0; e < 8; ++e) s += sS[t][e];
    sInv[t] = 1.0f / s;
  }
  __syncthreads();

  // epilogue: zq = acc / S
  #pragma unroll
  for (int r = 0; r < 8; ++r){
    const int lr = tg*8 + r;
    const int gi = (lr < 32) ? (i0 + lr) : (i0 + lr - 32 + HALF_ROWS);
    const float inv = sInv[lr];
    float4 o0v, o1v;
    o0v.x = acc[r][0]*inv; o0v.y = acc[r][1]*inv;
    o0v.z = acc[r][2]*inv; o0v.w = acc[r][3]*inv;
    o1v.x = acc[r][4]*inv; o1v.y = acc[r][5]*inv;
    o1v.z = acc[r][6]*inv; o1v.w = acc[r][7]*inv;
    *(float4*)&zq[(size_t)gi*DIM + td*8]     = o0v;
    *(float4*)&zq[(size_t)gi*DIM + td*8 + 4] = o1v;
  }
}

// ---------------- launch ----------------------------------------------------
extern "C" void kernel_launch(void* const* d_in, const int* in_sizes, int n_in,
                              void* d_out, int out_size, void* d_ws, size_t ws_size,
                              hipStream_t stream)
{
  (void)in_sizes; (void)n_in; (void)out_size; (void)ws_size;
  const float* z    = (const float*)d_in[0];
  const float* cp   = (const float*)d_in[1];
  const float* lpq  = (const float*)d_in[2];
  const float* book = (const float*)d_in[3];
  const float* mu   = (const float*)d_in[4];
  const int*   temp = (const int*)d_in[5];
  // d_in[6] = is_train, unused by the reference computation

  float* out = (float*)d_out;
  float* zq  = out;             // also used as zp scratch between K1 and K3
  float* pqo = out + OFF_PQ;
  float* lg  = out + OFF_LG;
  float* mm  = out + OFF_MM;

  float* ws  = (float*)d_ws;    // needs ~270 KB
  float* bn  = ws;
  float* rn  = ws + WS_RN;
  float* wpq = ws + WS_PQ;

  hipLaunchKernelGGL(k_prep,   dim3(BOOKN), dim3(256), 0, stream,
                     book, lpq, bn, wpq, pqo);
  hipLaunchKernelGGL(k_mix,    dim3(NPTS), dim3(256), 0, stream,
                     z, cp, mu, zq, mm, rn);
  hipLaunchKernelGGL(k_logits, dim3(BOOKN/JT, NROWS/IT), dim3(256), 0, stream,
                     zq, book, rn, bn, wpq, lg);
  hipLaunchKernelGGL(k_zq,     dim3(HALF_ROWS/32), dim3(256), 0, stream,
                     lg, book, temp, zq);
}